// Round 12
// baseline (487.640 us; speedup 1.0000x reference)
//
#include <hip/hip_runtime.h>

// ConvGeodesic: B=50000, R=5, A=8, K=2, O=32, I=32
// conv[b,n] = sum_k p[b,k] * W[k,n]   (M=50000, K=1280, N=256)
//   p[b,(ra,i)] = sum_t bary[b,ra,t]*signal[b,ra,t,i]
//   W[(ra,i),(c,o)] = sum_kk kernel[r,(c+a)%8,kk,o,i]
// R12: WAVE-INDEPENDENT tiling. One wave owns a 16-row x 256-col tile:
//  - pullback is lane-local (A-frag row = lane&15, k-slice = (lane>>4)*8),
//    so NO LDS, NO barriers, NO inter-wave coupling anywhere.
//  - 3125 independent waves self-stagger; TLP provides the memory parallelism
//    the lockstepped 64-row blocks (R5-R10, all ~230us) never achieved.
//  - arithmetic = R8's proven 3-term bf16 hi/lo split (fp16 failed: argmax
//    flip window ~ conv err; fp16's 0.1-0.5 err -> absmax 27. bf16 3-term
//    err ~1e-3 -> absmax 0.125).
//  - epilogue LDS-free: shfl_xor norm reduce over col-lanes, cndmask select.
// out[b,:] = relu(conv)[b, argmax_c ||relu(conv)[b,c,:]||, :]

#define B_TOT 50000
#define NRA 40
#define NROWTILES 3125   // 50000/16 exactly — no edge clamps

typedef __attribute__((ext_vector_type(8))) short short8v;   // 8 bf16 (4 VGPRs)
typedef __attribute__((ext_vector_type(4))) float f32x4;

// W planes, n-major k-minor per ra-slab: [ra][n=256][k'=32] bf16 (1.31 MB total)
__device__ __align__(16) unsigned short W_hi_g[NRA * 256 * 32];
__device__ __align__(16) unsigned short W_lo_g[NRA * 256 * 32];

static __device__ __forceinline__ unsigned short f2bf(float x) {   // rne
    unsigned u = __float_as_uint(x);
    u += 0x7FFFu + ((u >> 16) & 1u);
    return (unsigned short)(u >> 16);
}
static __device__ __forceinline__ float bf2f(unsigned short h) {
    return __uint_as_float(((unsigned)h) << 16);
}

__global__ __launch_bounds__(256) void build_w_kernel(const float* __restrict__ kern) {
    int e = blockIdx.x * 256 + threadIdx.x;   // e = ((ra*256)+n)*32 + i
    int i = e & 31;
    int n = (e >> 5) & 255;
    int ra = e >> 13;
    int r = ra >> 3, a = ra & 7;
    int c = n >> 5, o = n & 31;
    int a2 = (c + a) & 7;
    // kernel (R,A,K,O,I); kk stride = 1024
    const float* p = kern + ((((r * 8 + a2) * 2) * 32 + o) * 32 + i);
    float w = p[0] + p[1024];
    unsigned short hi = f2bf(w);
    unsigned short lo = f2bf(w - bf2f(hi));
    W_hi_g[e] = hi;
    W_lo_g[e] = lo;
}

__global__ __launch_bounds__(256) void conv_geo_kernel(const float* __restrict__ sig,
                                                       const float* __restrict__ bary,
                                                       float* __restrict__ out) {
    const int tid  = threadIdx.x;
    const int lane = tid & 63;
    const int wv   = tid >> 6;
    const int rt   = blockIdx.x * 4 + wv;        // wave's 16-row tile
    if (rt >= NROWTILES) return;                  // wave-uniform exit

    const int arow = lane & 15;                   // A-frag row this lane feeds
    const int i0   = (lane >> 4) * 8;             // k-slice within ra-chunk
    const size_t srow = ((size_t)rt * 16 + arow) * 40;

    f32x4 acc[16];                                // one 16x16 tile per ni
#pragma unroll
    for (int ni = 0; ni < 16; ++ni) acc[ni] = (f32x4){0.f, 0.f, 0.f, 0.f};

    const int wbase = arow * 32 + (lane >> 4) * 8;   // W frag lane offset (halves)

    for (int ra = 0; ra < NRA; ++ra) {
        // ---- lane-local pullback: 24 sig floats + 3 bary -> p[8] ----
        const float* sp = sig + (srow + ra) * 96 + i0;
        float4 t0a = *(const float4*)(sp);       float4 t0b = *(const float4*)(sp + 4);
        float4 t1a = *(const float4*)(sp + 32);  float4 t1b = *(const float4*)(sp + 36);
        float4 t2a = *(const float4*)(sp + 64);  float4 t2b = *(const float4*)(sp + 68);
        const float* bp = bary + (srow + ra) * 3;
        float by0 = bp[0], by1 = bp[1], by2 = bp[2];
        float p[8];
        p[0] = fmaf(by2, t2a.x, fmaf(by1, t1a.x, by0 * t0a.x));
        p[1] = fmaf(by2, t2a.y, fmaf(by1, t1a.y, by0 * t0a.y));
        p[2] = fmaf(by2, t2a.z, fmaf(by1, t1a.z, by0 * t0a.z));
        p[3] = fmaf(by2, t2a.w, fmaf(by1, t1a.w, by0 * t0a.w));
        p[4] = fmaf(by2, t2b.x, fmaf(by1, t1b.x, by0 * t0b.x));
        p[5] = fmaf(by2, t2b.y, fmaf(by1, t1b.y, by0 * t0b.y));
        p[6] = fmaf(by2, t2b.z, fmaf(by1, t1b.z, by0 * t0b.z));
        p[7] = fmaf(by2, t2b.w, fmaf(by1, t1b.w, by0 * t0b.w));
        unsigned short hh[8], ll[8];
#pragma unroll
        for (int j = 0; j < 8; ++j) {
            hh[j] = f2bf(p[j]);
            ll[j] = f2bf(p[j] - bf2f(hh[j]));
        }
        union { unsigned u[4]; short8v v; } ch, cl;
#pragma unroll
        for (int k = 0; k < 4; ++k) {
            ch.u[k] = (unsigned)hh[2 * k] | ((unsigned)hh[2 * k + 1] << 16);
            cl.u[k] = (unsigned)ll[2 * k] | ((unsigned)ll[2 * k + 1] << 16);
        }
        short8v ah = ch.v, al = cl.v;

        // ---- 16 n-tiles: stream W frags from L2, 3-term MFMA ----
        const unsigned short* wh = W_hi_g + ra * 8192 + wbase;
        const unsigned short* wl = W_lo_g + ra * 8192 + wbase;
#pragma unroll
        for (int ni = 0; ni < 16; ++ni) {
            short8v bh = *(const short8v*)(wh + ni * 512);
            short8v bl = *(const short8v*)(wl + ni * 512);
            acc[ni] = __builtin_amdgcn_mfma_f32_16x16x32_bf16(ah, bh, acc[ni], 0, 0, 0);
            acc[ni] = __builtin_amdgcn_mfma_f32_16x16x32_bf16(ah, bl, acc[ni], 0, 0, 0);
            acc[ni] = __builtin_amdgcn_mfma_f32_16x16x32_bf16(al, bh, acc[ni], 0, 0, 0);
        }
    }

    // ---- epilogue (LDS-free): relu -> norms -> shfl-reduce -> argmax -> select ----
    // D layout (m89): within tile ni: col = lane&15, row = (lane>>4)*4 + j.
#pragma unroll
    for (int ni = 0; ni < 16; ++ni)
#pragma unroll
        for (int j = 0; j < 4; ++j) acc[ni][j] = fmaxf(acc[ni][j], 0.0f);

    float nrm[4][8];                              // [j][c] partial: this lane's col
#pragma unroll
    for (int j = 0; j < 4; ++j)
#pragma unroll
        for (int c = 0; c < 8; ++c)
            nrm[j][c] = fmaf(acc[2 * c][j], acc[2 * c][j],
                             acc[2 * c + 1][j] * acc[2 * c + 1][j]);
#pragma unroll
    for (int m = 1; m < 16; m <<= 1)              // reduce over the 16 col-lanes
#pragma unroll
        for (int j = 0; j < 4; ++j)
#pragma unroll
            for (int c = 0; c < 8; ++c)
                nrm[j][c] += __shfl_xor(nrm[j][c], m, 64);

#pragma unroll
    for (int j = 0; j < 4; ++j) {
        float n2 = nrm[j][0];
        int bc = 0;
#pragma unroll
        for (int c = 1; c < 8; ++c)               // strict > keeps lowest c on tie
            if (nrm[j][c] > n2) { n2 = nrm[j][c]; bc = c; }
        float v0 = acc[0][j], v1 = acc[1][j];     // static-index select (rule #20)
#pragma unroll
        for (int c = 1; c < 8; ++c)
            if (bc == c) { v0 = acc[2 * c][j]; v1 = acc[2 * c + 1][j]; }
        int b = rt * 16 + (lane >> 4) * 4 + j;
        out[(size_t)b * 32 + (lane & 15)]      = v0;   // o = 0..15
        out[(size_t)b * 32 + 16 + (lane & 15)] = v1;   // o = 16..31
    }
}

extern "C" void kernel_launch(void* const* d_in, const int* in_sizes, int n_in,
                              void* d_out, int out_size, void* d_ws, size_t ws_size,
                              hipStream_t stream) {
    const float* sig  = (const float*)d_in[0];   // (B,R,A,3,I)
    const float* bary = (const float*)d_in[1];   // (B,R,A,3)
    const float* kern = (const float*)d_in[2];   // (R,A,K,O,I)
    float* out = (float*)d_out;                  // (B,O)

    build_w_kernel<<<(NRA * 256 * 32) / 256, 256, 0, stream>>>(kern);
    conv_geo_kernel<<<(NROWTILES + 3) / 4, 256, 0, stream>>>(sig, bary, out);
}

// Round 13
// 229.116 us; speedup vs baseline: 2.1284x; 2.1284x over previous
//
#include <hip/hip_runtime.h>

// ConvGeodesic: B=50000, R=5, A=8, K=2, O=32, I=32
// conv[b,n] = sum_k p[b,k] * W[k,n]   (M=50000, K=1280, N=256)
//   p[b,(ra,i)] = sum_t bary[b,ra,t]*signal[b,ra,t,i]
//   W[(ra,i),(c,o)] = sum_kk kernel[r,(c+a)%8,kk,o,i]
// R13: DMA ring done right. 3 half-slot (32row x 384B) LDS ring filled by
// global_load_lds ~1.5 iters ahead. KEY FIX vs R10/R8: vmcnt is FIFO — any
// load consumed after the ring DMAs are issued forces a vmcnt(0) drain of the
// ring (R10's hidden bug). So each iter issues bary+W FIRST, ring DMAs LAST:
// MFMA's W-wait becomes vmcnt(6), leaving the ring in flight permanently.
// Pullback is COOPERATIVE (from LDS sig tile -> p_lds), not per-lane redundant
// (R10's 4x VALU bug). Arithmetic = R8's proven 3-term bf16 hi/lo split.
// LDS 45056B -> LDS-capped 3 blocks/CU; NO reg-cap launch_bounds (R7/R9 spills).
// out[b,:] = relu(conv)[b, argmax_c ||relu(conv)[b,c,:]||, :]

#define B_TOT 50000
#define NRA 40
#define SLOT_B 12288          // 32 rows x 384 B
#define P_OFF  36864          // p_lds after 3 slots; hi [64][32]h + lo at +4096B

typedef __attribute__((ext_vector_type(8))) short short8v;   // 8 bf16 (4 VGPRs)
typedef __attribute__((ext_vector_type(4))) float f32x4;
typedef const __attribute__((address_space(1))) unsigned int* gp1_t;
typedef __attribute__((address_space(3))) unsigned int* lp3_t;

// W planes, n-major k-minor per ra-slab: [ra][n=256][k'=32] bf16 (1.31 MB each)
__device__ __align__(16) unsigned short W_hi_g[NRA * 256 * 32];
__device__ __align__(16) unsigned short W_lo_g[NRA * 256 * 32];

static __device__ __forceinline__ unsigned short f2bf(float x) {   // rne
    unsigned u = __float_as_uint(x);
    u += 0x7FFFu + ((u >> 16) & 1u);
    return (unsigned short)(u >> 16);
}
static __device__ __forceinline__ float bf2f(unsigned short h) {
    return __uint_as_float(((unsigned)h) << 16);
}

__global__ __launch_bounds__(256) void build_w_kernel(const float* __restrict__ kern) {
    int e = blockIdx.x * 256 + threadIdx.x;   // e = ((ra*256)+n)*32 + i
    int i = e & 31;
    int n = (e >> 5) & 255;
    int ra = e >> 13;
    int r = ra >> 3, a = ra & 7;
    int c = n >> 5, o = n & 31;
    int a2 = (c + a) & 7;
    // kernel (R,A,K,O,I); kk stride = 1024
    const float* p = kern + ((((r * 8 + a2) * 2) * 32 + o) * 32 + i);
    float w = p[0] + p[1024];
    unsigned short hi = f2bf(w);
    unsigned short lo = f2bf(w - bf2f(hi));
    W_hi_g[e] = hi;
    W_lo_g[e] = lo;
}

static __device__ __forceinline__ void pcomp(float by0, float by1, float by2,
                                             const float4& a, const float4& b,
                                             const float4& c, float* d) {
    d[0] = fmaf(by2, c.x, fmaf(by1, b.x, by0 * a.x));
    d[1] = fmaf(by2, c.y, fmaf(by1, b.y, by0 * a.y));
    d[2] = fmaf(by2, c.z, fmaf(by1, b.z, by0 * a.z));
    d[3] = fmaf(by2, c.w, fmaf(by1, b.w, by0 * a.w));
}

__global__ __launch_bounds__(256) void conv_geo_kernel(const float* __restrict__ sig,
                                                       const float* __restrict__ bary,
                                                       float* __restrict__ out) {
    __shared__ __align__(16) char lds_raw[45056];

    const int tid  = threadIdx.x;
    const int lane = tid & 63;
    const int wave = tid >> 6;       // 4 waves, wave w owns cols [64w, 64w+64)
    const int b_l  = tid >> 2;       // 0..63: pullback row
    const int q    = tid & 3;
    const int b0   = blockIdx.x * 64;
    int bld = b0 + b_l; if (bld > B_TOT - 1) bld = B_TOT - 1;   // clamp; stores guarded

    f32x4 acc[4][4];                 // [mi][ni]
#pragma unroll
    for (int mi = 0; mi < 4; ++mi)
#pragma unroll
        for (int ni = 0; ni < 4; ++ni) acc[mi][ni] = (f32x4){0.f, 0.f, 0.f, 0.f};

    const int wcol  = (wave * 64 + (lane & 15)) * 32 + (lane >> 4) * 8; // W frag base
    const int pbase = (lane & 15) * 32 + (lane >> 4) * 8;               // A-frag base (halves)
    const int widx  = b_l * 32 + q * 4;                                 // p write base (halves)

    // ---- DMA source offsets (pre-inverse-swizzled global cols; m173 pattern) ----
    unsigned offA[3], offB[3];       // parity 0: rows 0..31; parity 1: rows 32..63
#pragma unroll
    for (int j = 0; j < 3; ++j) {
        int L   = j * 4096 + tid * 16;
        int rIH = L / 384;                      // row in half, 0..31
        int col = L - rIH * 384;
        int scol = col ^ ((rIH & 7) << 4);      // involution within 128B
        int r0 = b0 + rIH;      if (r0 > B_TOT - 1) r0 = B_TOT - 1;
        int r1 = b0 + 32 + rIH; if (r1 > B_TOT - 1) r1 = B_TOT - 1;
        offA[j] = (unsigned)r0 * 15360u + (unsigned)scol;
        offB[j] = (unsigned)r1 * 15360u + (unsigned)scol;
    }
    const char* sigc = (const char*)sig;
    auto issueA = [&](int rra, int slot) {      // half0 of tile rra -> slot
#pragma unroll
        for (int j = 0; j < 3; ++j) {
            const void* gp = sigc + ((size_t)offA[j] + (size_t)rra * 384u);
            void* lp = lds_raw + slot * SLOT_B + j * 4096 + tid * 16;
            __builtin_amdgcn_global_load_lds((gp1_t)gp, (lp3_t)lp, 16, 0, 0);
        }
    };
    auto issueB = [&](int rra, int slot) {      // half1 of tile rra -> slot
#pragma unroll
        for (int j = 0; j < 3; ++j) {
            const void* gp = sigc + ((size_t)offB[j] + (size_t)rra * 384u);
            void* lp = lds_raw + slot * SLOT_B + j * 4096 + tid * 16;
            __builtin_amdgcn_global_load_lds((gp1_t)gp, (lp3_t)lp, 16, 0, 0);
        }
    };

    // prologue: halves h0,h1,h2 -> slots 0,1,2 (9 DMAs in flight)
    issueA(0, 0);
    issueB(0, 1);
    issueA(1, 2);

    int sA = 0, sB = 1;              // slots holding half0(ra), half1(ra)
    unsigned short* p_w = (unsigned short*)(lds_raw + P_OFF);
    const unsigned short* p_r = (const unsigned short*)(lds_raw + P_OFF);
    const int rIHme = b_l & 31;
    const int hfme  = b_l >> 5;
    const int swzP  = (b_l & 7) << 4;

#pragma unroll 1
    for (int ra = 0; ra < NRA; ++ra) {
        // ---- slot-ready: wait OWN 2 halves (leave next half's 3 in flight) ----
        if (ra < NRA - 1) asm volatile("s_waitcnt vmcnt(3) lgkmcnt(0)" ::: "memory");
        else              asm volatile("s_waitcnt vmcnt(0) lgkmcnt(0)" ::: "memory");
        __builtin_amdgcn_s_barrier();
        asm volatile("" ::: "memory");

        // ---- consumable loads FIRST (FIFO: keep ring DMAs youngest) ----
        const float* bp = bary + (size_t)bld * 120 + ra * 3;
        float by0 = bp[0], by1 = bp[1], by2 = bp[2];
        short8v bh[4], bl[4];
        {
            const unsigned short* wh = W_hi_g + ra * 8192 + wcol;
            const unsigned short* wl = W_lo_g + ra * 8192 + wcol;
#pragma unroll
            for (int ni = 0; ni < 4; ++ni) {
                bh[ni] = *(const short8v*)(wh + ni * 512);
                bl[ni] = *(const short8v*)(wl + ni * 512);
            }
        }

        // ---- cooperative pullback from LDS sig -> p_lds (bf16 hi/lo) ----
        {
            int slotSel = hfme ? sB : sA;
            const char* rowp = lds_raw + slotSel * SLOT_B + rIHme * 384;
            float4 s0 = *(const float4*)(rowp + ((q * 16)      ^ swzP));
            float4 s1 = *(const float4*)(rowp + ((q * 16 + 64) ^ swzP));
            float4 s2 = *(const float4*)(rowp + (((q * 16)      ^ swzP) + 128));
            float4 s3 = *(const float4*)(rowp + (((q * 16 + 64) ^ swzP) + 128));
            float4 s4 = *(const float4*)(rowp + (((q * 16)      ^ swzP) + 256));
            float4 s5 = *(const float4*)(rowp + (((q * 16 + 64) ^ swzP) + 256));
            float pa[4], pb2[4];
            pcomp(by0, by1, by2, s0, s2, s4, pa);    // i = 4q..4q+3
            pcomp(by0, by1, by2, s1, s3, s5, pb2);   // i = 4q+16..4q+19
            unsigned short h1[4], l1[4], h2[4], l2[4];
#pragma unroll
            for (int k = 0; k < 4; ++k) {
                h1[k] = f2bf(pa[k]);  l1[k] = f2bf(pa[k]  - bf2f(h1[k]));
                h2[k] = f2bf(pb2[k]); l2[k] = f2bf(pb2[k] - bf2f(h2[k]));
            }
            uint2 H1, H2, L1, L2;
            H1.x = (unsigned)h1[0] | ((unsigned)h1[1] << 16);
            H1.y = (unsigned)h1[2] | ((unsigned)h1[3] << 16);
            H2.x = (unsigned)h2[0] | ((unsigned)h2[1] << 16);
            H2.y = (unsigned)h2[2] | ((unsigned)h2[3] << 16);
            L1.x = (unsigned)l1[0] | ((unsigned)l1[1] << 16);
            L1.y = (unsigned)l1[2] | ((unsigned)l1[3] << 16);
            L2.x = (unsigned)l2[0] | ((unsigned)l2[1] << 16);
            L2.y = (unsigned)l2[2] | ((unsigned)l2[3] << 16);
            *(uint2*)(p_w + widx)               = H1;
            *(uint2*)(p_w + widx + 16)          = H2;
            *(uint2*)(p_w + 2048 + widx)        = L1;
            *(uint2*)(p_w + 2048 + widx + 16)   = L2;
        }

        // ---- p-ready barrier (lgkm only; ring stays in flight) ----
        asm volatile("s_waitcnt lgkmcnt(0)" ::: "memory");
        __builtin_amdgcn_s_barrier();
        asm volatile("" ::: "memory");

        // ---- ring refill LAST (youngest vmem -> W waits leave these alone) ----
        if (ra + 1 < NRA) issueB(ra + 1, sA);   // h(2ra+3) into just-freed slot
        if (ra + 2 < NRA) issueA(ra + 2, sB);   // h(2ra+4)
        sA += 2; if (sA >= 3) sA -= 3;
        sB += 2; if (sB >= 3) sB -= 3;

        // ---- MFMA: A-frags from p_lds, 3-term bf16 ----
#pragma unroll
        for (int mi = 0; mi < 4; ++mi) {
            const unsigned short* pr = p_r + mi * 512 + pbase;
            short8v ah = *(const short8v*)pr;
            short8v al = *(const short8v*)(pr + 2048);
#pragma unroll
            for (int ni = 0; ni < 4; ++ni) {
                acc[mi][ni] = __builtin_amdgcn_mfma_f32_16x16x32_bf16(ah, bh[ni], acc[mi][ni], 0, 0, 0);
                acc[mi][ni] = __builtin_amdgcn_mfma_f32_16x16x32_bf16(ah, bl[ni], acc[mi][ni], 0, 0, 0);
                acc[mi][ni] = __builtin_amdgcn_mfma_f32_16x16x32_bf16(al, bh[ni], acc[mi][ni], 0, 0, 0);
            }
        }
    }

    // ---- epilogue: relu + norms + argmax + select, two 32-row passes ----
    // D layout: row = 16*mi + 4*(lane>>4) + j, col = 64*wave + 16*ni + (lane&15)
    float* smem = (float*)lds_raw;   // [32][264]
    const int colb = wave * 64 + (lane & 15);
    const int rsub = (lane >> 4) * 4;
#pragma unroll
    for (int ph = 0; ph < 2; ++ph) {
        __syncthreads();
#pragma unroll
        for (int mh = 0; mh < 2; ++mh) {
            int mi = ph * 2 + mh;
#pragma unroll
            for (int ni = 0; ni < 4; ++ni)
#pragma unroll
                for (int j = 0; j < 4; ++j)
                    smem[(mh * 16 + rsub + j) * 264 + colb + ni * 16] =
                        fmaxf(acc[mi][ni][j], 0.0f);
        }
        __syncthreads();
        int bb = tid >> 3;          // 0..31
        int c  = tid & 7;
        float n2 = 0.0f;
#pragma unroll
        for (int t = 0; t < 8; ++t) {
            float4 v = *(const float4*)&smem[bb * 264 + c * 32 + t * 4];
            n2 = fmaf(v.x, v.x, n2); n2 = fmaf(v.y, v.y, n2);
            n2 = fmaf(v.z, v.z, n2); n2 = fmaf(v.w, v.w, n2);
        }
        int bc = c;
#pragma unroll
        for (int m = 1; m < 8; m <<= 1) {   // argmax, tie -> lowest c (numpy first-max)
            float on2 = __shfl_xor(n2, m, 64);
            int obc = __shfl_xor(bc, m, 64);
            if (on2 > n2 || (on2 == n2 && obc < bc)) { n2 = on2; bc = obc; }
        }
        int b = b0 + ph * 32 + bb;
        if (b < B_TOT) {
            float4 v = *(const float4*)&smem[bb * 264 + bc * 32 + (tid & 7) * 4];
            *(float4*)&out[(size_t)b * 32 + (tid & 7) * 4] = v;
        }
    }
}

extern "C" void kernel_launch(void* const* d_in, const int* in_sizes, int n_in,
                              void* d_out, int out_size, void* d_ws, size_t ws_size,
                              hipStream_t stream) {
    const float* sig  = (const float*)d_in[0];   // (B,R,A,3,I)
    const float* bary = (const float*)d_in[1];   // (B,R,A,3)
    const float* kern = (const float*)d_in[2];   // (R,A,K,O,I)
    float* out = (float*)d_out;                  // (B,O)

    build_w_kernel<<<(NRA * 256 * 32) / 256, 256, 0, stream>>>(kern);
    conv_geo_kernel<<<(B_TOT + 63) / 64, 256, 0, stream>>>(sig, bary, out);
}